// Round 2
// baseline (3398.265 us; speedup 1.0000x reference)
//
#include <hip/hip_runtime.h>

// ---------------------------------------------------------------------------
// peepLSTM  (B=512, S=256, H=768, E=6, C=10, V=3) — split-precision MFMA
//
//  * 192 persistent blocks = 16 col-groups (32 batch) x 12 row-blocks (64 h),
//    512 threads (8 waves): waves 0-3 f-gate, 4-7 i-gate (rows sub*16..+15).
//  * W_fh/W_ih held per-wave in VGPRs as bf16 hi+lo (24 frags each).
//  * c exchanged as bf16 hi+lo planes (~16-bit mantissa); master c fp32 regs.
//  * z = Whi*chi + Whi*clo + Wlo*chi  (3 MFMAs/term-group, fp32 accum).
//  * o-gate only at last step (f-waves reload Woh into the same registers).
//  * per-group 12-block barrier: agent-scope release RMW / acquire load.
// ---------------------------------------------------------------------------

typedef __bf16 bf16x8 __attribute__((ext_vector_type(8)));
typedef __bf16 bf16x4 __attribute__((ext_vector_type(4)));
typedef float  f32x4  __attribute__((ext_vector_type(4)));

#define Hdim  768
#define Bdim  512
#define Sdim  256
#define NSTEP 255
#define Edim  6
#define NCls  10
#define NGRP  16
#define NRB   12
#define GC    32
#define HB    64
#define NKK   24
#define CSTR  776            // LDS c stride (768+8): 2-way banks only (free)
#define XSTR  260
#define PLANE (Bdim * Hdim)  // bf16 elements per c plane

#define WS_CBUF_BYTES  (4u * PLANE * 2u)            // 2 bufs x (hi+lo) bf16
#define WS_HFIN_OFF    (WS_CBUF_BYTES)
#define WS_BAR_OFF     (WS_HFIN_OFF + Bdim * Hdim * 4u)
#define WS_BAR_BYTES   (NGRP * 32u * 4u)

__device__ __forceinline__ float sigf(float z) {
    return 1.0f / (1.0f + __expf(-z));
}

__device__ __forceinline__ void split8(const float* __restrict__ p,
                                       bf16x8& hi, bf16x8& lo) {
    #pragma unroll
    for (int j = 0; j < 8; ++j) {
        const float v = p[j];
        const __bf16 h = (__bf16)v;
        hi[j] = h;
        lo[j] = (__bf16)(v - (float)h);
    }
}

__global__ void __launch_bounds__(512, 2)
lstm_persist(const int* __restrict__ xk, const float* __restrict__ emb,
             const float* __restrict__ Wfx, const float* __restrict__ Wfh, const float* __restrict__ bfv,
             const float* __restrict__ Wix, const float* __restrict__ Wih, const float* __restrict__ biv,
             const float* __restrict__ Wox, const float* __restrict__ Woh, const float* __restrict__ bov,
             const float* __restrict__ Wcx, const float* __restrict__ bcv,
             const float* __restrict__ cinit,
             __bf16* __restrict__ cbuf, float* __restrict__ hfin,
             unsigned int* __restrict__ bar)
{
    __shared__ __align__(16) __bf16 ldsH[GC * CSTR];          // 49,664 B
    __shared__ __align__(16) __bf16 ldsL[GC * CSTR];          // 49,664 B
    __shared__ __align__(16) float  tbl[3 * HB * 4];          //  3,072 B [v][hl][f,i,o,sig_c]
    __shared__ __align__(16) float  zbuf[HB * GC];            //  8,192 B (z_i exchange)
    __shared__ __align__(4)  unsigned char xtok[GC * XSTR];   //  8,320 B
    __shared__ int s_flag;

    const int tid  = threadIdx.x;
    const int w    = tid >> 6;
    const int lane = tid & 63;
    const int q    = lane >> 4;
    const int r    = lane & 15;
    const int gt   = w >> 2;            // 0 = f-gate waves, 1 = i-gate waves
    const int sub  = w & 3;             // row sub-block within the 64
    const int bid  = blockIdx.x;
    const int g    = bid & 15;
    const int rb   = bid >> 4;
    const int blkh0 = rb * HB;
    const int gc0   = g * GC;
    const int arow  = blkh0 + sub * 16 + r;       // A-frag row (m = lane&15)
    const int hq0   = blkh0 + sub * 16 + q * 4;   // C-frag row of reg 0

    // ---- int64-vs-int32 token layout detector (odd int32 words all-zero => int64)
    if (tid == 0) s_flag = 0;
    __syncthreads();
    if (tid < 256) {
        const int wv = xk[(size_t)gc0 * Sdim + 2 * tid + 1];
        if (wv != 0) s_flag = 1;
    }
    // ---- per-token gate bias tables (embedding path collapsed) ----
    if (tid < 3 * HB) {
        const int v  = tid >> 6;
        const int hl = tid & 63;
        const int hg = blkh0 + hl;
        float pf = bfv[hg], pi = biv[hg], po = bov[hg], pc = bcv[hg];
        #pragma unroll
        for (int e = 0; e < Edim; ++e) {
            const float ev = emb[v * Edim + e];
            pf += Wfx[hg * Edim + e] * ev;
            pi += Wix[hg * Edim + e] * ev;
            po += Wox[hg * Edim + e] * ev;
            pc += Wcx[hg * Edim + e] * ev;
        }
        float* t = &tbl[(v * HB + hl) * 4];
        t[0] = pf; t[1] = pi; t[2] = po; t[3] = sigf(pc);
    }
    __syncthreads();
    const int is64 = (s_flag == 0);

    // ---- token staging (scalar, one-time) ----
    {
        const int col   = tid >> 4;
        const int sbase = (tid & 15) * 16;
        const size_t rowb = (size_t)(gc0 + col) * Sdim;
        for (int k2 = 0; k2 < 16; ++k2) {
            const int s0 = sbase + k2;
            const size_t idx = rowb + s0;
            xtok[col * XSTR + s0] = (unsigned char)xk[is64 ? (idx << 1) : idx];
        }
    }

    // ---- persistent W fragments (hi+lo) for this wave's gate ----
    const float* Wg = gt ? Wih : Wfh;
    bf16x8 ahi[NKK], alo[NKK];
    #pragma unroll
    for (int kk = 0; kk < NKK; ++kk)
        split8(&Wg[(size_t)arow * Hdim + kk * 32 + q * 8], ahi[kk], alo[kk]);

    // ---- persistent fp32 c state (C-fragment layout; only f-waves use it) ----
    float cst[2][4];
    #pragma unroll
    for (int ct = 0; ct < 2; ++ct) {
        const int b = gc0 + ct * 16 + r;
        #pragma unroll
        for (int reg = 0; reg < 4; ++reg)
            cst[ct][reg] = cinit[(size_t)(hq0 + reg) * Bdim + b];
    }

    // ---- step-0 LDS staging from c_init (fp32 [h][b] -> hi/lo bf16 [col][k]) ----
    for (int i = 0; i < 48; ++i) {
        const int idx = tid + i * 512;
        const int col = idx & 31, k = idx >> 5;
        const float v = cinit[(size_t)k * Bdim + gc0 + col];
        const __bf16 h = (__bf16)v;
        ldsH[col * CSTR + k] = h;
        ldsL[col * CSTR + k] = (__bf16)(v - (float)h);
    }

    for (int s = 0; s < NSTEP; ++s) {
        __syncthreads();                                     // S1: tiles ready

        f32x4 a0 = {0.f,0.f,0.f,0.f}, a1 = {0.f,0.f,0.f,0.f};
        #pragma unroll
        for (int kk = 0; kk < NKK; ++kk) {
            const int lo_off = kk * 32 + q * 8;
            const bf16x8 bh0 = *(const bf16x8*)&ldsH[ r       * CSTR + lo_off];
            const bf16x8 bl0 = *(const bf16x8*)&ldsL[ r       * CSTR + lo_off];
            const bf16x8 bh1 = *(const bf16x8*)&ldsH[(16 + r) * CSTR + lo_off];
            const bf16x8 bl1 = *(const bf16x8*)&ldsL[(16 + r) * CSTR + lo_off];
            a0 = __builtin_amdgcn_mfma_f32_16x16x32_bf16(ahi[kk], bh0, a0, 0, 0, 0);
            a0 = __builtin_amdgcn_mfma_f32_16x16x32_bf16(alo[kk], bh0, a0, 0, 0, 0);
            a0 = __builtin_amdgcn_mfma_f32_16x16x32_bf16(ahi[kk], bl0, a0, 0, 0, 0);
            a1 = __builtin_amdgcn_mfma_f32_16x16x32_bf16(ahi[kk], bh1, a1, 0, 0, 0);
            a1 = __builtin_amdgcn_mfma_f32_16x16x32_bf16(alo[kk], bh1, a1, 0, 0, 0);
            a1 = __builtin_amdgcn_mfma_f32_16x16x32_bf16(ahi[kk], bl1, a1, 0, 0, 0);
        }
        if (gt) {                                            // i-waves export z_i
            #pragma unroll
            for (int ct = 0; ct < 2; ++ct) {
                const f32x4 z = ct ? a1 : a0;
                #pragma unroll
                for (int reg = 0; reg < 4; ++reg)
                    zbuf[(sub * 16 + q * 4 + reg) * GC + ct * 16 + r] = z[reg];
            }
        }
        __syncthreads();                                     // S2: zbuf ready

        if (!gt) {
            if (s != NSTEP - 1) {
                __bf16* cwH = cbuf + (size_t)((s + 1) & 1) * (2 * PLANE);
                __bf16* cwL = cwH + PLANE;
                #pragma unroll
                for (int ct = 0; ct < 2; ++ct) {
                    const int bl = ct * 16 + r;
                    const int v  = xtok[bl * XSTR + s];
                    const float* tb = &tbl[(v * HB + sub * 16 + q * 4) * 4];
                    const f32x4 zf = ct ? a1 : a0;
                    bf16x4 cvh, cvl;
                    #pragma unroll
                    for (int reg = 0; reg < 4; ++reg) {
                        const float zi = zbuf[(sub * 16 + q * 4 + reg) * GC + bl];
                        const float* tt = tb + reg * 4;
                        const float fg = sigf(zf[reg] + tt[0]);
                        const float ig = sigf(zi + tt[1]);
                        const float cn = tt[3] * ig + cst[ct][reg] * fg;
                        cst[ct][reg] = cn;
                        const __bf16 ch = (__bf16)cn;
                        cvh[reg] = ch;
                        cvl[reg] = (__bf16)(cn - (float)ch);
                    }
                    *(bf16x4*)&cwH[(size_t)(gc0 + bl) * Hdim + hq0] = cvh;
                    *(bf16x4*)&cwL[(size_t)(gc0 + bl) * Hdim + hq0] = cvl;
                }
            } else {
                // ---- last step: reuse W registers for Woh, compute o-gate ----
                #pragma unroll
                for (int kk = 0; kk < NKK; ++kk)
                    split8(&Woh[(size_t)arow * Hdim + kk * 32 + q * 8], ahi[kk], alo[kk]);
                f32x4 o0 = {0.f,0.f,0.f,0.f}, o1 = {0.f,0.f,0.f,0.f};
                #pragma unroll
                for (int kk = 0; kk < NKK; ++kk) {
                    const int lo_off = kk * 32 + q * 8;
                    const bf16x8 bh0 = *(const bf16x8*)&ldsH[ r       * CSTR + lo_off];
                    const bf16x8 bl0 = *(const bf16x8*)&ldsL[ r       * CSTR + lo_off];
                    const bf16x8 bh1 = *(const bf16x8*)&ldsH[(16 + r) * CSTR + lo_off];
                    const bf16x8 bl1 = *(const bf16x8*)&ldsL[(16 + r) * CSTR + lo_off];
                    o0 = __builtin_amdgcn_mfma_f32_16x16x32_bf16(ahi[kk], bh0, o0, 0, 0, 0);
                    o0 = __builtin_amdgcn_mfma_f32_16x16x32_bf16(alo[kk], bh0, o0, 0, 0, 0);
                    o0 = __builtin_amdgcn_mfma_f32_16x16x32_bf16(ahi[kk], bl0, o0, 0, 0, 0);
                    o1 = __builtin_amdgcn_mfma_f32_16x16x32_bf16(ahi[kk], bh1, o1, 0, 0, 0);
                    o1 = __builtin_amdgcn_mfma_f32_16x16x32_bf16(alo[kk], bh1, o1, 0, 0, 0);
                    o1 = __builtin_amdgcn_mfma_f32_16x16x32_bf16(ahi[kk], bl1, o1, 0, 0, 0);
                }
                #pragma unroll
                for (int ct = 0; ct < 2; ++ct) {
                    const int bl = ct * 16 + r;
                    const int v  = xtok[bl * XSTR + s];
                    const float* tb = &tbl[(v * HB + sub * 16 + q * 4) * 4];
                    const f32x4 zf = ct ? a1 : a0;
                    const f32x4 zo = ct ? o1 : o0;
                    f32x4 hv;
                    #pragma unroll
                    for (int reg = 0; reg < 4; ++reg) {
                        const float zi = zbuf[(sub * 16 + q * 4 + reg) * GC + bl];
                        const float* tt = tb + reg * 4;
                        const float fg = sigf(zf[reg] + tt[0]);
                        const float ig = sigf(zi + tt[1]);
                        const float og = sigf(zo[reg] + tt[2]);
                        const float cn = tt[3] * ig + cst[ct][reg] * fg;
                        const float e  = __expf(-2.0f * fabsf(cn));
                        const float th = __builtin_copysignf((1.0f - e) / (1.0f + e), cn);
                        hv[reg] = th * og;
                    }
                    *(f32x4*)&hfin[(size_t)(gc0 + bl) * Hdim + hq0] = hv;
                }
            }
        }

        if (s < NSTEP - 1) {
            __syncthreads();                                 // S3: stores drained
            if (tid == 0) {
                const unsigned tgt = (unsigned)(NRB * (s + 1));
                unsigned int* cnt = &bar[g * 32];
                __hip_atomic_fetch_add(cnt, 1u, __ATOMIC_RELEASE, __HIP_MEMORY_SCOPE_AGENT);
                while (__hip_atomic_load(cnt, __ATOMIC_RELAXED, __HIP_MEMORY_SCOPE_AGENT) < tgt)
                    __builtin_amdgcn_s_sleep(1);
                (void)__hip_atomic_load(cnt, __ATOMIC_ACQUIRE, __HIP_MEMORY_SCOPE_AGENT);
            }
            __syncthreads();                                 // S4: barrier passed
            const __bf16* crH = cbuf + (size_t)((s + 1) & 1) * (2 * PLANE);
            const __bf16* crL = crH + PLANE;
            const int col = tid >> 4, j = tid & 15;
            const size_t rowo = (size_t)(gc0 + col) * Hdim;
            #pragma unroll
            for (int i = 0; i < 6; ++i) {
                const int k0 = (j + 16 * i) * 8;
                *(bf16x8*)&ldsH[col * CSTR + k0] = *(const bf16x8*)&crH[rowo + k0];
                *(bf16x8*)&ldsL[col * CSTR + k0] = *(const bf16x8*)&crL[rowo + k0];
            }
        }
    }
}

__global__ void __launch_bounds__(64)
proj_kernel(const float* __restrict__ hfin, const float* __restrict__ Wph,
            const float* __restrict__ bpv, float* __restrict__ out)
{
    const int b = blockIdx.x;
    const int lane = threadIdx.x;
    float acc[NCls];
    #pragma unroll
    for (int c = 0; c < NCls; ++c) acc[c] = 0.f;
    const float* hb = &hfin[(size_t)b * Hdim];
    for (int i = 0; i < Hdim / 64; ++i) {
        const float hv = hb[lane + i * 64];
        #pragma unroll
        for (int c = 0; c < NCls; ++c)
            acc[c] += Wph[c * Hdim + lane + i * 64] * hv;
    }
    #pragma unroll
    for (int c = 0; c < NCls; ++c) {
        float v = acc[c];
        #pragma unroll
        for (int off = 32; off > 0; off >>= 1)
            v += __shfl_xor(v, off, 64);
        acc[c] = v + bpv[c];
    }
    float m = acc[0];
    #pragma unroll
    for (int c = 1; c < NCls; ++c) m = fmaxf(m, acc[c]);
    float ssum = 0.f;
    #pragma unroll
    for (int c = 0; c < NCls; ++c) ssum += __expf(acc[c] - m);
    const float lse = m + __logf(ssum);
    if (lane < NCls) out[b * NCls + lane] = acc[lane] - lse;
}

extern "C" void kernel_launch(void* const* d_in, const int* in_sizes, int n_in,
                              void* d_out, int out_size, void* d_ws, size_t ws_size,
                              hipStream_t stream)
{
    const int*   xk    = (const int*)d_in[0];
    const float* emb   = (const float*)d_in[1];
    const float* Wfx   = (const float*)d_in[2];
    const float* Wfh   = (const float*)d_in[3];
    const float* bfv   = (const float*)d_in[4];
    const float* Wix   = (const float*)d_in[5];
    const float* Wih   = (const float*)d_in[6];
    const float* biv   = (const float*)d_in[7];
    const float* Wox   = (const float*)d_in[8];
    const float* Woh   = (const float*)d_in[9];
    const float* bov   = (const float*)d_in[10];
    const float* Wcx   = (const float*)d_in[11];
    const float* bcv   = (const float*)d_in[12];
    const float* Wph   = (const float*)d_in[13];
    const float* bpv   = (const float*)d_in[14];
    const float* cinit = (const float*)d_in[15];

    char* ws = (char*)d_ws;
    __bf16*       cbuf = (__bf16*)ws;
    float*        hfin = (float*)(ws + WS_HFIN_OFF);
    unsigned int* bar  = (unsigned int*)(ws + WS_BAR_OFF);

    hipMemsetAsync(bar, 0, WS_BAR_BYTES, stream);

    lstm_persist<<<dim3(NGRP * NRB), dim3(512), 0, stream>>>(
        xk, emb, Wfx, Wfh, bfv, Wix, Wih, biv, Wox, Woh, bov, Wcx, bcv,
        cinit, cbuf, hfin, bar);

    proj_kernel<<<dim3(Bdim), dim3(64), 0, stream>>>(hfin, Wph, bpv, (float*)d_out);
}

// Round 3
// 2196.360 us; speedup vs baseline: 1.5472x; 1.5472x over previous
//
#include <hip/hip_runtime.h>

// ---------------------------------------------------------------------------
// peepLSTM (B=512,S=256,H=768,E=6,C=10,V=3) — fp16 split MFMA, fence-free sync
//
//  * 192 persistent blocks = 16 col-groups (32 batch) x 12 row-blocks (64 h),
//    512 thr (8 waves): waves 0-3 f-gate, 4-7 i-gate.
//  * W prepacked (prep kernel) into fp16 hi/lo fragment-ordered planes in ws.
//    hi persists in VGPRs (96/lane); lo streamed from L2 each step.
//    lo plane scaled x4096 (denormal-proof); separate accumulator, combined
//    in epilogue: z = acc_h + acc_x * 2^-12.
//  * c master state fp32 in registers; exchanged as fp16 hi + (mid*4096)
//    planes via RELAXED agent-scope atomics (sc1 -> LLC-coherent, no wbl2/inv).
//  * Group barrier: per-block epoch slot (16 u32/group = one 64B line),
//    wave-0 12-lane poll. Ordering via the vmcnt(0) drain in __syncthreads.
// ---------------------------------------------------------------------------

typedef _Float16 f16x8 __attribute__((ext_vector_type(8)));
typedef _Float16 f16x4 __attribute__((ext_vector_type(4)));
typedef float    f32x4 __attribute__((ext_vector_type(4)));

#define Hdim  768
#define Bdim  512
#define Sdim  256
#define NSTEP 255
#define Edim  6
#define NCls  10
#define NGRP  16
#define NRB   12
#define GC    32
#define HB    64
#define NKK   24
#define CSTR  776
#define XSTR  260
#define PLANE (Bdim * Hdim)          // fp16 elems per c plane (393216)
#define SCL      4096.0f
#define SCL_INV  2.44140625e-4f      // 2^-12

#define WP_FRAGS   (2 * NRB * 4 * NKK * 64)         // 147456 fragments (16B each)
#define WS_CBUF    0u                               // 2 bufs x 2 planes x PLANE fp16
#define WS_HFIN    (2u * 2u * PLANE * 2u)           // 3,145,728
#define WS_BAR     (WS_HFIN + Bdim * Hdim * 4u)     // 4,718,592
#define WS_WPK     (WS_BAR + 4096u)                 // 4,722,688
#define WS_BAR_BYTES (NGRP * 16u * 4u)              // 1024

__device__ __forceinline__ float sigf(float z) { return 1.0f / (1.0f + __expf(-z)); }

__device__ __forceinline__ f32x4 mf(f16x8 a, f16x8 b, f32x4 c) {
    return __builtin_amdgcn_mfma_f32_16x16x32_f16(a, b, c, 0, 0, 0);
}

// ---------------- prep: split W into fp16 hi / (lo*4096) fragment planes ----
__global__ void __launch_bounds__(256)
prep_w(const float* __restrict__ Wfh, const float* __restrict__ Wih,
       _Float16* __restrict__ wpk)
{
    const int fid  = blockIdx.x * 256 + threadIdx.x;   // 0..147455
    const int lane = fid & 63;
    const int t1   = fid >> 6;            // gi*24 + kk
    const int kk   = t1 % NKK;
    const int gi   = t1 / NKK;            // (gate*12+rb)*4+sub
    const int sub  = gi & 3;
    const int t3   = gi >> 2;
    const int rb   = t3 % NRB;
    const int gate = t3 / NRB;
    const int q = lane >> 4, r = lane & 15;
    const int row = rb * 64 + sub * 16 + r;
    const int col = kk * 32 + q * 8;
    const float* src = (gate ? Wih : Wfh) + (size_t)row * Hdim + col;
    f16x8 hi, lo;
    #pragma unroll
    for (int j = 0; j < 8; ++j) {
        const float v = src[j];
        const _Float16 h = (_Float16)v;
        hi[j] = h;
        lo[j] = (_Float16)((v - (float)h) * SCL);
    }
    *(f16x8*)&wpk[(size_t)fid * 8] = hi;
    *(f16x8*)&wpk[((size_t)WP_FRAGS + fid) * 8] = lo;
}

// ---------------- main persistent kernel ------------------------------------
__global__ void __launch_bounds__(512, 2)
lstm_persist(const int* __restrict__ xk, const float* __restrict__ emb,
             const float* __restrict__ Wfx, const float* __restrict__ bfv,
             const float* __restrict__ Wix, const float* __restrict__ biv,
             const float* __restrict__ Wox, const float* __restrict__ Woh,
             const float* __restrict__ bov,
             const float* __restrict__ Wcx, const float* __restrict__ bcv,
             const float* __restrict__ cinit,
             const _Float16* __restrict__ wpk,
             _Float16* __restrict__ cbuf, float* __restrict__ hfin,
             unsigned int* __restrict__ bar)
{
    __shared__ __align__(16) _Float16 ldsH[GC * CSTR];        // 49,664 B
    __shared__ __align__(16) _Float16 ldsM[GC * CSTR];        // 49,664 B
    __shared__ __align__(16) float    tbl[3 * HB * 4];        //  3,072 B
    __shared__ __align__(16) float    zbuf[HB * GC];          //  8,192 B
    __shared__ __align__(4)  unsigned char xtok[GC * XSTR];   //  8,320 B
    __shared__ int s_flag;

    const int tid  = threadIdx.x;
    const int w    = tid >> 6;
    const int lane = tid & 63;
    const int q    = lane >> 4;
    const int r    = lane & 15;
    const int gt   = w >> 2;            // 0 = f-waves, 1 = i-waves
    const int sub  = w & 3;
    const int bid  = blockIdx.x;
    const int g    = bid & 15;
    const int rb   = bid >> 4;
    const int blkh0 = rb * HB;
    const int gc0   = g * GC;
    const int hq0   = blkh0 + sub * 16 + q * 4;
    const int gi    = (gt * NRB + rb) * 4 + sub;

    if (tid == 0) s_flag = 0;
    __syncthreads();
    if (tid < 256) {
        if (xk[(size_t)gc0 * Sdim + 2 * tid + 1] != 0) s_flag = 1;
    }
    if (tid < 3 * HB) {
        const int v  = tid >> 6;
        const int hl = tid & 63;
        const int hg = blkh0 + hl;
        float pf = bfv[hg], pi = biv[hg], po = bov[hg], pc = bcv[hg];
        #pragma unroll
        for (int e = 0; e < Edim; ++e) {
            const float ev = emb[v * Edim + e];
            pf += Wfx[hg * Edim + e] * ev;
            pi += Wix[hg * Edim + e] * ev;
            po += Wox[hg * Edim + e] * ev;
            pc += Wcx[hg * Edim + e] * ev;
        }
        float* t = &tbl[(v * HB + hl) * 4];
        t[0] = pf; t[1] = pi; t[2] = po; t[3] = sigf(pc);
    }
    __syncthreads();
    const int is64 = (s_flag == 0);

    {   // tokens -> LDS bytes
        const int col   = tid >> 4;
        const int sbase = (tid & 15) * 16;
        const size_t rowb = (size_t)(gc0 + col) * Sdim;
        for (int k2 = 0; k2 < 16; ++k2) {
            const int s0 = sbase + k2;
            const size_t idx = rowb + s0;
            xtok[col * XSTR + s0] = (unsigned char)xk[is64 ? (idx << 1) : idx];
        }
    }

    // persistent W-hi fragments for this wave's gate/rows
    f16x8 whi[NKK];
    #pragma unroll
    for (int kk = 0; kk < NKK; ++kk)
        whi[kk] = *(const f16x8*)&wpk[((size_t)(gi * NKK + kk) * 64 + lane) * 8];
    const _Float16* wloB = wpk + ((size_t)WP_FRAGS + (size_t)(gi * NKK) * 64 + lane) * 8;

    // persistent fp32 c state (C-frag layout; used by f-waves)
    float cst[2][4];
    #pragma unroll
    for (int ct = 0; ct < 2; ++ct) {
        const int b = gc0 + ct * 16 + r;
        #pragma unroll
        for (int reg = 0; reg < 4; ++reg)
            cst[ct][reg] = cinit[(size_t)(hq0 + reg) * Bdim + b];
    }

    // step-0 LDS tiles from c_init
    for (int i = 0; i < 48; ++i) {
        const int idx = tid + i * 512;
        const int col = idx & 31, k = idx >> 5;
        const float v = cinit[(size_t)k * Bdim + gc0 + col];
        const _Float16 h = (_Float16)v;
        ldsH[col * CSTR + k] = h;
        ldsM[col * CSTR + k] = (_Float16)((v - (float)h) * SCL);
    }

    for (int s = 0; s < NSTEP; ++s) {
        __syncthreads();                              // S1: tiles ready

        f32x4 a0h = {0,0,0,0}, a0x = {0,0,0,0}, a1h = {0,0,0,0}, a1x = {0,0,0,0};
        #pragma unroll
        for (int kk = 0; kk < NKK; ++kk) {
            const f16x8 wl = *(const f16x8*)&wloB[(size_t)kk * 64 * 8];
            const int lo = kk * 32 + q * 8;
            const f16x8 bh0 = *(const f16x8*)&ldsH[ r       * CSTR + lo];
            const f16x8 bm0 = *(const f16x8*)&ldsM[ r       * CSTR + lo];
            const f16x8 bh1 = *(const f16x8*)&ldsH[(16 + r) * CSTR + lo];
            const f16x8 bm1 = *(const f16x8*)&ldsM[(16 + r) * CSTR + lo];
            a0h = mf(whi[kk], bh0, a0h);
            a0x = mf(whi[kk], bm0, a0x);
            a0x = mf(wl,      bh0, a0x);
            a1h = mf(whi[kk], bh1, a1h);
            a1x = mf(whi[kk], bm1, a1x);
            a1x = mf(wl,      bh1, a1x);
        }
        if (gt) {                                     // i-waves export z_i
            #pragma unroll
            for (int ct = 0; ct < 2; ++ct) {
                const f32x4 zh = ct ? a1h : a0h;
                const f32x4 zx = ct ? a1x : a0x;
                #pragma unroll
                for (int reg = 0; reg < 4; ++reg)
                    zbuf[(sub * 16 + q * 4 + reg) * GC + ct * 16 + r] =
                        zh[reg] + zx[reg] * SCL_INV;
            }
        }
        __syncthreads();                              // S2: zbuf ready

        if (!gt) {
            if (s != NSTEP - 1) {
                _Float16* cwH = cbuf + (size_t)(((s + 1) & 1) * 2) * PLANE;
                _Float16* cwM = cwH + PLANE;
                #pragma unroll
                for (int ct = 0; ct < 2; ++ct) {
                    const int bl = ct * 16 + r;
                    const int v  = xtok[bl * XSTR + s];
                    const float* tb = &tbl[(v * HB + sub * 16 + q * 4) * 4];
                    const f32x4 zh = ct ? a1h : a0h;
                    const f32x4 zx = ct ? a1x : a0x;
                    f16x4 cvh, cvm;
                    #pragma unroll
                    for (int reg = 0; reg < 4; ++reg) {
                        const float zf = zh[reg] + zx[reg] * SCL_INV;
                        const float zi = zbuf[(sub * 16 + q * 4 + reg) * GC + bl];
                        const float* tt = tb + reg * 4;
                        const float fg = sigf(zf + tt[0]);
                        const float ig = sigf(zi + tt[1]);
                        const float cn = tt[3] * ig + cst[ct][reg] * fg;
                        cst[ct][reg] = cn;
                        const _Float16 ch = (_Float16)cn;
                        cvh[reg] = ch;
                        cvm[reg] = (_Float16)((cn - (float)ch) * SCL);
                    }
                    unsigned long long uh, um;
                    __builtin_memcpy(&uh, &cvh, 8);
                    __builtin_memcpy(&um, &cvm, 8);
                    const size_t eo = (size_t)(gc0 + bl) * Hdim + hq0;
                    __hip_atomic_store((unsigned long long*)&cwH[eo], uh,
                                       __ATOMIC_RELAXED, __HIP_MEMORY_SCOPE_AGENT);
                    __hip_atomic_store((unsigned long long*)&cwM[eo], um,
                                       __ATOMIC_RELAXED, __HIP_MEMORY_SCOPE_AGENT);
                }
            } else {
                // last step: o-gate from fp32 Woh (hi-only fp16), h = tanh(c)*o
                f32x4 o0h = {0,0,0,0}, o0x = {0,0,0,0}, o1h = {0,0,0,0}, o1x = {0,0,0,0};
                const int arow = blkh0 + sub * 16 + r;
                #pragma unroll
                for (int kk = 0; kk < NKK; ++kk) {
                    const float* wp = Woh + (size_t)arow * Hdim + kk * 32 + q * 8;
                    f16x8 who;
                    #pragma unroll
                    for (int j = 0; j < 8; ++j) who[j] = (_Float16)wp[j];
                    const int lo = kk * 32 + q * 8;
                    const f16x8 bh0 = *(const f16x8*)&ldsH[ r       * CSTR + lo];
                    const f16x8 bm0 = *(const f16x8*)&ldsM[ r       * CSTR + lo];
                    const f16x8 bh1 = *(const f16x8*)&ldsH[(16 + r) * CSTR + lo];
                    const f16x8 bm1 = *(const f16x8*)&ldsM[(16 + r) * CSTR + lo];
                    o0h = mf(who, bh0, o0h);  o0x = mf(who, bm0, o0x);
                    o1h = mf(who, bh1, o1h);  o1x = mf(who, bm1, o1x);
                }
                #pragma unroll
                for (int ct = 0; ct < 2; ++ct) {
                    const int bl = ct * 16 + r;
                    const int v  = xtok[bl * XSTR + s];
                    const float* tb = &tbl[(v * HB + sub * 16 + q * 4) * 4];
                    const f32x4 zh = ct ? a1h : a0h;
                    const f32x4 zx = ct ? a1x : a0x;
                    const f32x4 zoh = ct ? o1h : o0h;
                    const f32x4 zox = ct ? o1x : o0x;
                    f32x4 hv;
                    #pragma unroll
                    for (int reg = 0; reg < 4; ++reg) {
                        const float zf = zh[reg] + zx[reg] * SCL_INV;
                        const float zi = zbuf[(sub * 16 + q * 4 + reg) * GC + bl];
                        const float zo = zoh[reg] + zox[reg] * SCL_INV;
                        const float* tt = tb + reg * 4;
                        const float fg = sigf(zf + tt[0]);
                        const float ig = sigf(zi + tt[1]);
                        const float og = sigf(zo + tt[2]);
                        const float cn = tt[3] * ig + cst[ct][reg] * fg;
                        const float e  = __expf(-2.0f * fabsf(cn));
                        const float th = __builtin_copysignf((1.0f - e) / (1.0f + e), cn);
                        hv[reg] = th * og;
                    }
                    *(f32x4*)&hfin[(size_t)(gc0 + bl) * Hdim + hq0] = hv;
                }
            }
        }

        if (s < NSTEP - 1) {
            asm volatile("s_waitcnt vmcnt(0)" ::: "memory");
            __syncthreads();                          // S3: all c stores at LLC
            if (w == 0) {
                if (lane == 0)
                    __hip_atomic_store(&bar[g * 16 + rb], (unsigned)(s + 1),
                                       __ATOMIC_RELAXED, __HIP_MEMORY_SCOPE_AGENT);
                const unsigned tgt = (unsigned)(s + 1);
                while (true) {
                    unsigned vv = tgt;
                    if (lane < NRB)
                        vv = __hip_atomic_load(&bar[g * 16 + lane],
                                               __ATOMIC_RELAXED, __HIP_MEMORY_SCOPE_AGENT);
                    if (__all(vv >= tgt)) break;
                    __builtin_amdgcn_s_sleep(2);
                }
            }
            __syncthreads();                          // S4: barrier passed
            // stage next c tiles (LLC-coherent loads, 24 x 8B per thread)
            const _Float16* crH = cbuf + (size_t)(((s + 1) & 1) * 2) * PLANE;
            const _Float16* crM = crH + PLANE;
            const int col = tid >> 4, j = tid & 15;
            const size_t rowo = (size_t)(gc0 + col) * Hdim;
            unsigned long long th[12], tm[12];
            #pragma unroll
            for (int i = 0; i < 12; ++i)
                th[i] = __hip_atomic_load((unsigned long long*)&crH[rowo + (j + 16 * i) * 4],
                                          __ATOMIC_RELAXED, __HIP_MEMORY_SCOPE_AGENT);
            #pragma unroll
            for (int i = 0; i < 12; ++i)
                tm[i] = __hip_atomic_load((unsigned long long*)&crM[rowo + (j + 16 * i) * 4],
                                          __ATOMIC_RELAXED, __HIP_MEMORY_SCOPE_AGENT);
            #pragma unroll
            for (int i = 0; i < 12; ++i) {
                *(unsigned long long*)&ldsH[col * CSTR + (j + 16 * i) * 4] = th[i];
                *(unsigned long long*)&ldsM[col * CSTR + (j + 16 * i) * 4] = tm[i];
            }
        }
    }
}

__global__ void __launch_bounds__(64)
proj_kernel(const float* __restrict__ hfin, const float* __restrict__ Wph,
            const float* __restrict__ bpv, float* __restrict__ out)
{
    const int b = blockIdx.x;
    const int lane = threadIdx.x;
    float acc[NCls];
    #pragma unroll
    for (int c = 0; c < NCls; ++c) acc[c] = 0.f;
    const float* hb = &hfin[(size_t)b * Hdim];
    for (int i = 0; i < Hdim / 64; ++i) {
        const float hv = hb[lane + i * 64];
        #pragma unroll
        for (int c = 0; c < NCls; ++c)
            acc[c] += Wph[c * Hdim + lane + i * 64] * hv;
    }
    #pragma unroll
    for (int c = 0; c < NCls; ++c) {
        float v = acc[c];
        #pragma unroll
        for (int off = 32; off > 0; off >>= 1)
            v += __shfl_xor(v, off, 64);
        acc[c] = v + bpv[c];
    }
    float m = acc[0];
    #pragma unroll
    for (int c = 1; c < NCls; ++c) m = fmaxf(m, acc[c]);
    float ssum = 0.f;
    #pragma unroll
    for (int c = 0; c < NCls; ++c) ssum += __expf(acc[c] - m);
    const float lse = m + __logf(ssum);
    if (lane < NCls) out[b * NCls + lane] = acc[lane] - lse;
}

extern "C" void kernel_launch(void* const* d_in, const int* in_sizes, int n_in,
                              void* d_out, int out_size, void* d_ws, size_t ws_size,
                              hipStream_t stream)
{
    const int*   xk    = (const int*)d_in[0];
    const float* emb   = (const float*)d_in[1];
    const float* Wfx   = (const float*)d_in[2];
    const float* Wfh   = (const float*)d_in[3];
    const float* bfv   = (const float*)d_in[4];
    const float* Wix   = (const float*)d_in[5];
    const float* Wih   = (const float*)d_in[6];
    const float* biv   = (const float*)d_in[7];
    const float* Wox   = (const float*)d_in[8];
    const float* Woh   = (const float*)d_in[9];
    const float* bov   = (const float*)d_in[10];
    const float* Wcx   = (const float*)d_in[11];
    const float* bcv   = (const float*)d_in[12];
    const float* Wph   = (const float*)d_in[13];
    const float* bpv   = (const float*)d_in[14];
    const float* cinit = (const float*)d_in[15];

    char* ws = (char*)d_ws;
    _Float16*     cbuf = (_Float16*)(ws + WS_CBUF);
    float*        hfin = (float*)(ws + WS_HFIN);
    unsigned int* bar  = (unsigned int*)(ws + WS_BAR);
    _Float16*     wpk  = (_Float16*)(ws + WS_WPK);

    hipMemsetAsync(bar, 0, WS_BAR_BYTES, stream);

    prep_w<<<dim3(WP_FRAGS / 256), dim3(256), 0, stream>>>(Wfh, Wih, wpk);

    lstm_persist<<<dim3(NGRP * NRB), dim3(512), 0, stream>>>(
        xk, emb, Wfx, bfv, Wix, biv, Wox, Woh, bov, Wcx, bcv,
        cinit, wpk, cbuf, hfin, bar);

    proj_kernel<<<dim3(Bdim), dim3(64), 0, stream>>>(hfin, Wph, bpv, (float*)d_out);
}